// Round 1
// baseline (1944.140 us; speedup 1.0000x reference)
//
#include <hip/hip_runtime.h>
#include <math.h>

#define NN    2048     // nodes
#define NE    32768    // edges
#define NP    262144   // edge-edge pairs
#define CS_   384
#define CZ_   128
#define CG_   16
#define NRBF_ 64

// ---------------- K1: node_left / node_right projections ----------------
__global__ void k_nodeproj(const float* __restrict__ nf,
                           const float* __restrict__ wnl, const float* __restrict__ bnl,
                           const float* __restrict__ wnr, const float* __restrict__ bnr,
                           float* __restrict__ nl, float* __restrict__ nr) {
  const int n = blockIdx.x;
  const int t = threadIdx.x;
  if (t >= 32) return;
  const float* __restrict__ w = (t < 16) ? wnl : wnr;
  const int col = t & 15;
  const float* __restrict__ row = nf + (size_t)n * CS_;
  float acc = 0.f;
  #pragma unroll 8
  for (int k = 0; k < CS_; ++k) acc = fmaf(row[k], w[k * CG_ + col], acc);
  acc += (t < 16) ? bnl[col] : bnr[col];
  ((t < 16) ? nl : nr)[n * CG_ + col] = acc;
}

// ------- K2: edge2 = sigmoid(LN(src)@w_eg+b_eg) * (LN(src)@w_ep+b_ep) -------
__global__ __launch_bounds__(256) void k_edge2(
    const float* __restrict__ sef,
    const float* __restrict__ gs, const float* __restrict__ bs,
    const float* __restrict__ weg, const float* __restrict__ beg,
    const float* __restrict__ wep, const float* __restrict__ bep,
    float* __restrict__ edge2) {
  __shared__ float xln[32][132];
  const int tid = threadIdx.x;
  const int row0 = blockIdx.x * 32;
  {
    const int r = tid >> 3, s = tid & 7;
    const float* __restrict__ xp = sef + (size_t)(row0 + r) * CZ_ + s * 16;
    float v[16];
    #pragma unroll
    for (int q = 0; q < 4; ++q) {
      const float4 t4 = *(const float4*)(xp + 4 * q);
      v[4*q+0] = t4.x; v[4*q+1] = t4.y; v[4*q+2] = t4.z; v[4*q+3] = t4.w;
    }
    float sum = 0.f, sq = 0.f;
    #pragma unroll
    for (int q = 0; q < 16; ++q) { sum += v[q]; sq = fmaf(v[q], v[q], sq); }
    #pragma unroll
    for (int o = 1; o < 8; o <<= 1) { sum += __shfl_xor(sum, o); sq += __shfl_xor(sq, o); }
    const float mean = sum * (1.f / CZ_);
    const float rstd = rsqrtf(sq * (1.f / CZ_) - mean * mean + 1e-5f);
    const int kb = s * 16;
    #pragma unroll
    for (int q = 0; q < 16; ++q)
      xln[r][kb + q] = (v[q] - mean) * rstd * gs[kb + q] + bs[kb + q];
  }
  __syncthreads();

  const int c = tid & (CZ_ - 1);
  const int h = tid >> 7;
  float accg[16], accp[16];
  #pragma unroll
  for (int q = 0; q < 16; ++q) { accg[q] = 0.f; accp[q] = 0.f; }
  #pragma unroll 2
  for (int k = 0; k < CZ_; k += 4) {
    const float wg0 = weg[(size_t)(k+0)*CZ_ + c], wg1 = weg[(size_t)(k+1)*CZ_ + c],
                wg2 = weg[(size_t)(k+2)*CZ_ + c], wg3 = weg[(size_t)(k+3)*CZ_ + c];
    const float wp0 = wep[(size_t)(k+0)*CZ_ + c], wp1 = wep[(size_t)(k+1)*CZ_ + c],
                wp2 = wep[(size_t)(k+2)*CZ_ + c], wp3 = wep[(size_t)(k+3)*CZ_ + c];
    #pragma unroll
    for (int rr = 0; rr < 16; ++rr) {
      const float4 xv = *(const float4*)&xln[h*16 + rr][k];
      accg[rr] = fmaf(xv.x, wg0, accg[rr]); accg[rr] = fmaf(xv.y, wg1, accg[rr]);
      accg[rr] = fmaf(xv.z, wg2, accg[rr]); accg[rr] = fmaf(xv.w, wg3, accg[rr]);
      accp[rr] = fmaf(xv.x, wp0, accp[rr]); accp[rr] = fmaf(xv.y, wp1, accp[rr]);
      accp[rr] = fmaf(xv.z, wp2, accp[rr]); accp[rr] = fmaf(xv.w, wp3, accp[rr]);
    }
  }
  const float bg = beg[c], bp = bep[c];
  #pragma unroll
  for (int rr = 0; rr < 16; ++rr) {
    const float gate = 1.f / (1.f + __expf(-(accg[rr] + bg)));
    edge2[(size_t)(row0 + h*16 + rr) * CZ_ + c] = gate * (accp[rr] + bp);
  }
}

// ------- K3: per-pair gate GEMM + RBF dist features + atomic segment-sum -------
#define GJ(NRV) { \
    const float o_ = nli * (NRV); \
    _Pragma("unroll") \
    for (int t = 0; t < 16; ++t) { \
      const float4 w4 = *(const float4*)(wrow + 4 * t); \
      acc[4*t+0] = fmaf(o_, w4.x, acc[4*t+0]); \
      acc[4*t+1] = fmaf(o_, w4.y, acc[4*t+1]); \
      acc[4*t+2] = fmaf(o_, w4.z, acc[4*t+2]); \
      acc[4*t+3] = fmaf(o_, w4.w, acc[4*t+3]); \
    } \
    wrow += 64; }

__global__ __launch_bounds__(256) void k_pair(
    const int* __restrict__ ee,
    const int* __restrict__ sei, const int* __restrict__ dei,
    const float* __restrict__ nl, const float* __restrict__ nr,
    const float* __restrict__ trans,
    const float* __restrict__ wdg, const float* __restrict__ bdg,
    const float* __restrict__ wdp, const float* __restrict__ bdp,
    float* __restrict__ accum) {
  __shared__ float swdg[256][64];   // 64 KB: this block's channel-half of w_dg
  __shared__ float snl[16][256];    // 16 KB: transposed nl rows (conflict-free)
  const int tid = threadIdx.x;
  const int c0 = blockIdx.y * 64;

  #pragma unroll 4
  for (int idx = tid; idx < 256 * 64; idx += 256)
    swdg[idx >> 6][idx & 63] = wdg[(size_t)(idx >> 6) * CZ_ + c0 + (idx & 63)];

  const int p  = blockIdx.x * 256 + tid;
  const int e0 = ee[p];        // dst edge (segment id)
  const int e1 = ee[NP + p];   // src edge
  const int n1 = sei[e1];
  const int n2 = dei[e0];

  {
    const float4* __restrict__ L = (const float4*)(nl + (size_t)n1 * CG_);
    const float4 a = L[0], b = L[1], c2 = L[2], d = L[3];
    snl[0][tid]=a.x;  snl[1][tid]=a.y;  snl[2][tid]=a.z;  snl[3][tid]=a.w;
    snl[4][tid]=b.x;  snl[5][tid]=b.y;  snl[6][tid]=b.z;  snl[7][tid]=b.w;
    snl[8][tid]=c2.x; snl[9][tid]=c2.y; snl[10][tid]=c2.z; snl[11][tid]=c2.w;
    snl[12][tid]=d.x; snl[13][tid]=d.y; snl[14][tid]=d.z; snl[15][tid]=d.w;
  }
  const float4* __restrict__ Rp = (const float4*)(nr + (size_t)n2 * CG_);
  const float4 R0 = Rp[0], R1 = Rp[1], R2 = Rp[2], R3 = Rp[3];

  __syncthreads();

  float acc[64];
  #pragma unroll
  for (int t = 0; t < 16; ++t) {
    const float4 b4 = *(const float4*)(bdg + c0 + 4 * t);
    acc[4*t+0]=b4.x; acc[4*t+1]=b4.y; acc[4*t+2]=b4.z; acc[4*t+3]=b4.w;
  }

  // gate[c] = sum_{i,j} nl_i * nr_j * w_dg[i*16+j][c]
  #pragma unroll 1
  for (int i = 0; i < 16; ++i) {
    const float nli = snl[i][tid];
    const float* wrow = &swdg[i * 16][0];
    GJ(R0.x) GJ(R0.y) GJ(R0.z) GJ(R0.w)
    GJ(R1.x) GJ(R1.y) GJ(R1.z) GJ(R1.w)
    GJ(R2.x) GJ(R2.y) GJ(R2.z) GJ(R2.w)
    GJ(R3.x) GJ(R3.y) GJ(R3.z) GJ(R3.w)
  }

  #pragma unroll
  for (int t = 0; t < 64; ++t)
    acc[t] = __builtin_amdgcn_rcpf(1.f + __expf(-acc[t]));  // sigmoid

  const float dx = trans[n1*3+0] - trans[n2*3+0] + 1e-8f;
  const float dy = trans[n1*3+1] - trans[n2*3+1] + 1e-8f;
  const float dz = trans[n1*3+2] - trans[n2*3+2] + 1e-8f;
  const float dist = sqrtf(fmaf(dx, dx, fmaf(dy, dy, dz * dz)));

  float df[64];
  #pragma unroll
  for (int t = 0; t < 16; ++t) {
    const float4 b4 = *(const float4*)(bdp + c0 + 4 * t);
    df[4*t+0]=b4.x; df[4*t+1]=b4.y; df[4*t+2]=b4.z; df[4*t+3]=b4.w;
  }
  const float inv_sigma = (float)NRBF_ / 20.f;  // 1/sigma = 3.2
  #pragma unroll 2
  for (int rr = 0; rr < NRBF_; ++rr) {
    const float mu = (float)rr * (20.f / 63.f);     // linspace(0,20,64)
    const float u = (dist - mu) * inv_sigma;
    const float e = __expf(-u * u);
    const float* __restrict__ wp = wdp + (size_t)rr * CZ_ + c0;
    #pragma unroll
    for (int t = 0; t < 16; ++t) {
      const float4 w4 = *(const float4*)(wp + 4 * t);
      df[4*t+0] = fmaf(e, w4.x, df[4*t+0]);
      df[4*t+1] = fmaf(e, w4.y, df[4*t+1]);
      df[4*t+2] = fmaf(e, w4.z, df[4*t+2]);
      df[4*t+3] = fmaf(e, w4.w, df[4*t+3]);
    }
  }

  float* __restrict__ arow = accum + (size_t)e0 * CZ_ + c0;
  #pragma unroll
  for (int t = 0; t < 64; ++t)
    atomicAdd(arow + t, acc[t] * df[t]);
}

// ------- K4: out = (LN(edge2*segsum)@w_lo+b_lo) * sigmoid(LN(dst)@w_og+b_og) -------
__global__ __launch_bounds__(256) void k_final(
    const float* __restrict__ accum, const float* __restrict__ edge2,
    const float* __restrict__ def,
    const float* __restrict__ go, const float* __restrict__ bo,
    const float* __restrict__ gd, const float* __restrict__ bd,
    const float* __restrict__ wlo, const float* __restrict__ blo,
    const float* __restrict__ wog, const float* __restrict__ bog,
    float* __restrict__ out) {
  __shared__ float x1[32][132];
  __shared__ float x2[32][132];
  const int tid = threadIdx.x;
  const int row0 = blockIdx.x * 32;
  {
    const int r = tid >> 3, s = tid & 7;
    const int kb = s * 16;
    float v[16];
    {
      const float* __restrict__ ap = accum + (size_t)(row0 + r) * CZ_ + kb;
      const float* __restrict__ ep = edge2 + (size_t)(row0 + r) * CZ_ + kb;
      #pragma unroll
      for (int q = 0; q < 4; ++q) {
        const float4 a4 = *(const float4*)(ap + 4*q);
        const float4 b4 = *(const float4*)(ep + 4*q);
        v[4*q+0]=a4.x*b4.x; v[4*q+1]=a4.y*b4.y; v[4*q+2]=a4.z*b4.z; v[4*q+3]=a4.w*b4.w;
      }
      float sum = 0.f, sq = 0.f;
      #pragma unroll
      for (int q = 0; q < 16; ++q) { sum += v[q]; sq = fmaf(v[q], v[q], sq); }
      #pragma unroll
      for (int o = 1; o < 8; o <<= 1) { sum += __shfl_xor(sum, o); sq += __shfl_xor(sq, o); }
      const float mean = sum * (1.f / CZ_);
      const float rstd = rsqrtf(sq * (1.f / CZ_) - mean * mean + 1e-5f);
      #pragma unroll
      for (int q = 0; q < 16; ++q)
        x1[r][kb+q] = (v[q] - mean) * rstd * go[kb+q] + bo[kb+q];
    }
    {
      const float* __restrict__ dp = def + (size_t)(row0 + r) * CZ_ + kb;
      #pragma unroll
      for (int q = 0; q < 4; ++q) {
        const float4 a4 = *(const float4*)(dp + 4*q);
        v[4*q+0]=a4.x; v[4*q+1]=a4.y; v[4*q+2]=a4.z; v[4*q+3]=a4.w;
      }
      float sum = 0.f, sq = 0.f;
      #pragma unroll
      for (int q = 0; q < 16; ++q) { sum += v[q]; sq = fmaf(v[q], v[q], sq); }
      #pragma unroll
      for (int o = 1; o < 8; o <<= 1) { sum += __shfl_xor(sum, o); sq += __shfl_xor(sq, o); }
      const float mean = sum * (1.f / CZ_);
      const float rstd = rsqrtf(sq * (1.f / CZ_) - mean * mean + 1e-5f);
      #pragma unroll
      for (int q = 0; q < 16; ++q)
        x2[r][kb+q] = (v[q] - mean) * rstd * gd[kb+q] + bd[kb+q];
    }
  }
  __syncthreads();

  const int c = tid & (CZ_ - 1);
  const int h = tid >> 7;
  float accy[16], accg[16];
  #pragma unroll
  for (int q = 0; q < 16; ++q) { accy[q] = 0.f; accg[q] = 0.f; }
  #pragma unroll 2
  for (int k = 0; k < CZ_; k += 4) {
    const float wl0 = wlo[(size_t)(k+0)*CZ_ + c], wl1 = wlo[(size_t)(k+1)*CZ_ + c],
                wl2 = wlo[(size_t)(k+2)*CZ_ + c], wl3 = wlo[(size_t)(k+3)*CZ_ + c];
    const float wo0 = wog[(size_t)(k+0)*CZ_ + c], wo1 = wog[(size_t)(k+1)*CZ_ + c],
                wo2 = wog[(size_t)(k+2)*CZ_ + c], wo3 = wog[(size_t)(k+3)*CZ_ + c];
    #pragma unroll
    for (int rr = 0; rr < 16; ++rr) {
      const float4 xv1 = *(const float4*)&x1[h*16 + rr][k];
      const float4 xv2 = *(const float4*)&x2[h*16 + rr][k];
      accy[rr] = fmaf(xv1.x, wl0, accy[rr]); accy[rr] = fmaf(xv1.y, wl1, accy[rr]);
      accy[rr] = fmaf(xv1.z, wl2, accy[rr]); accy[rr] = fmaf(xv1.w, wl3, accy[rr]);
      accg[rr] = fmaf(xv2.x, wo0, accg[rr]); accg[rr] = fmaf(xv2.y, wo1, accg[rr]);
      accg[rr] = fmaf(xv2.z, wo2, accg[rr]); accg[rr] = fmaf(xv2.w, wo3, accg[rr]);
    }
  }
  const float bl = blo[c], bgv = bog[c];
  #pragma unroll
  for (int rr = 0; rr < 16; ++rr) {
    const float y = accy[rr] + bl;
    const float gsig = 1.f / (1.f + __expf(-(accg[rr] + bgv)));
    out[(size_t)(row0 + h*16 + rr) * CZ_ + c] = y * gsig;
  }
}

extern "C" void kernel_launch(void* const* d_in, const int* in_sizes, int n_in,
                              void* d_out, int out_size, void* d_ws, size_t ws_size,
                              hipStream_t stream) {
  const float* nf     = (const float*)d_in[0];
  const float* trans  = (const float*)d_in[1];
  const float* dst_ef = (const float*)d_in[2];
  const int*   dst_ei = (const int*)d_in[3];
  const float* src_ef = (const float*)d_in[4];
  const int*   src_ei = (const int*)d_in[5];
  const int*   ee     = (const int*)d_in[6];
  const float* w_nl  = (const float*)d_in[7];  const float* b_nl  = (const float*)d_in[8];
  const float* w_nr  = (const float*)d_in[9];  const float* b_nr  = (const float*)d_in[10];
  const float* g_dst = (const float*)d_in[11]; const float* bt_dst= (const float*)d_in[12];
  const float* g_src = (const float*)d_in[13]; const float* bt_src= (const float*)d_in[14];
  const float* w_ep  = (const float*)d_in[15]; const float* b_ep  = (const float*)d_in[16];
  const float* w_eg  = (const float*)d_in[17]; const float* b_eg  = (const float*)d_in[18];
  const float* w_dg  = (const float*)d_in[19]; const float* b_dg  = (const float*)d_in[20];
  const float* w_dp  = (const float*)d_in[21]; const float* b_dp  = (const float*)d_in[22];
  const float* g_out = (const float*)d_in[23]; const float* bt_out= (const float*)d_in[24];
  const float* w_lo  = (const float*)d_in[25]; const float* b_lo  = (const float*)d_in[26];
  const float* w_og  = (const float*)d_in[27]; const float* b_og  = (const float*)d_in[28];

  float* accum = (float*)d_ws;                       // [NE,128] f32 segment sums
  float* edge2 = accum + (size_t)NE * CZ_;           // [NE,128] f32
  float* nlbuf = edge2 + (size_t)NE * CZ_;           // [NN,16]
  float* nrbuf = nlbuf + (size_t)NN * CG_;           // [NN,16]

  hipMemsetAsync(accum, 0, (size_t)NE * CZ_ * sizeof(float), stream);
  k_nodeproj<<<NN, 64, 0, stream>>>(nf, w_nl, b_nl, w_nr, b_nr, nlbuf, nrbuf);
  k_edge2<<<NE / 32, 256, 0, stream>>>(src_ef, g_src, bt_src, w_eg, b_eg, w_ep, b_ep, edge2);
  k_pair<<<dim3(NP / 256, 2), 256, 0, stream>>>(ee, src_ei, dst_ei, nlbuf, nrbuf, trans,
                                                w_dg, b_dg, w_dp, b_dp, accum);
  k_final<<<NE / 32, 256, 0, stream>>>(accum, edge2, dst_ef, g_out, bt_out, g_dst, bt_dst,
                                       w_lo, b_lo, w_og, b_og, (float*)d_out);
}

// Round 2
// 231.237 us; speedup vs baseline: 8.4076x; 8.4076x over previous
//
#include <hip/hip_runtime.h>
#include <hip/hip_bf16.h>
#include <math.h>

#define NN    2048
#define NE    32768
#define NP    262144
#define CS_   384
#define CZ_   128
#define CG_   16
#define NRBF_ 64

typedef __attribute__((ext_vector_type(8))) short bf16x8;
typedef __attribute__((ext_vector_type(4))) float f32x4;

__device__ __forceinline__ unsigned short f2bf(float f) {
  __hip_bfloat16 h = __float2bfloat16(f);
  union { __hip_bfloat16 h; unsigned short u; } cv; cv.h = h; return cv.u;
}

// ---------------- K1: node projections -> bf16 rows ----------------
__global__ void k_nodeproj(const float* __restrict__ nf,
                           const float* __restrict__ wnl, const float* __restrict__ bnl,
                           const float* __restrict__ wnr, const float* __restrict__ bnr,
                           unsigned short* __restrict__ nl, unsigned short* __restrict__ nr) {
  const int n = blockIdx.x;
  const int t = threadIdx.x;
  if (t >= 32) return;
  const float* __restrict__ w = (t < 16) ? wnl : wnr;
  const int col = t & 15;
  const float* __restrict__ row = nf + (size_t)n * CS_;
  float acc = 0.f;
  #pragma unroll 8
  for (int k = 0; k < CS_; ++k) acc = fmaf(row[k], w[k * CG_ + col], acc);
  acc += (t < 16) ? bnl[col] : bnr[col];
  ((t < 16) ? nl : nr)[n * CG_ + col] = f2bf(acc);
}

// ---------------- K_prepB: weights -> MFMA-frag-ready bf16 layout ----------------
// Bfrag  (w_dg): idx = ((n*8+ks)*64 + l)*8 + e ; k = ks*32 + (l>>4)*8 + e ; ch = n*16 + (l&15)
// B2frag (w_dp): jdx = ((n*2+ks2)*64 + l)*8 + e; k2 = ks2*32 + (l>>4)*8 + e
__global__ void k_prepB(const float* __restrict__ wdg, const float* __restrict__ wdp,
                        unsigned short* __restrict__ frag) {
  const int idx = blockIdx.x * 256 + threadIdx.x;
  if (idx >= 40960) return;
  float v;
  if (idx < 32768) {
    const int e = idx & 7, l = (idx >> 3) & 63, ks = (idx >> 9) & 7, n = idx >> 12;
    const int k = ks * 32 + (l >> 4) * 8 + e, ch = n * 16 + (l & 15);
    v = wdg[(size_t)k * CZ_ + ch];
  } else {
    const int j = idx - 32768;
    const int e = j & 7, l = (j >> 3) & 63, ks2 = (j >> 9) & 1, n = j >> 10;
    const int k2 = ks2 * 32 + (l >> 4) * 8 + e, ch = n * 16 + (l & 15);
    v = wdp[(size_t)k2 * CZ_ + ch];
  }
  frag[idx] = f2bf(v);
}

// ---------------- sort machinery ----------------
__global__ void k_hist(const int* __restrict__ ee, int* __restrict__ hist) {
  const int p = blockIdx.x * 256 + threadIdx.x;
  atomicAdd(&hist[ee[p]], 1);
}

__global__ __launch_bounds__(1024) void k_scan(const int* __restrict__ hist,
                                               int* __restrict__ start) {
  __shared__ int tot[1024];
  const int t = threadIdx.x;
  const int base = t * 32;
  int s = 0;
  for (int k = 0; k < 32; ++k) s += hist[base + k];
  tot[t] = s;
  __syncthreads();
  for (int off = 1; off < 1024; off <<= 1) {
    int v = tot[t];
    int u = (t >= off) ? tot[t - off] : 0;
    __syncthreads();
    tot[t] = v + u;
    __syncthreads();
  }
  int run = (t == 0) ? 0 : tot[t - 1];
  for (int k = 0; k < 32; ++k) { start[base + k] = run; run += hist[base + k]; }
  if (t == 1023) start[32768] = run;
}

__global__ void k_scatter(const int* __restrict__ ee, const int* __restrict__ start,
                          int* __restrict__ cnt2, int* __restrict__ perm) {
  const int p = blockIdx.x * 256 + threadIdx.x;
  const int e = ee[p];
  const int idx = atomicAdd(&cnt2[e], 1);
  perm[start[e] + idx] = p;
}

// ------- K2: edge2 = sigmoid(LN(src)@w_eg+b_eg) * (LN(src)@w_ep+b_ep) -------
__global__ __launch_bounds__(256) void k_edge2(
    const float* __restrict__ sef,
    const float* __restrict__ gs, const float* __restrict__ bs,
    const float* __restrict__ weg, const float* __restrict__ beg,
    const float* __restrict__ wep, const float* __restrict__ bep,
    float* __restrict__ edge2) {
  __shared__ float xln[32][132];
  const int tid = threadIdx.x;
  const int row0 = blockIdx.x * 32;
  {
    const int r = tid >> 3, s = tid & 7;
    const float* __restrict__ xp = sef + (size_t)(row0 + r) * CZ_ + s * 16;
    float v[16];
    #pragma unroll
    for (int q = 0; q < 4; ++q) {
      const float4 t4 = *(const float4*)(xp + 4 * q);
      v[4*q+0] = t4.x; v[4*q+1] = t4.y; v[4*q+2] = t4.z; v[4*q+3] = t4.w;
    }
    float sum = 0.f, sq = 0.f;
    #pragma unroll
    for (int q = 0; q < 16; ++q) { sum += v[q]; sq = fmaf(v[q], v[q], sq); }
    #pragma unroll
    for (int o = 1; o < 8; o <<= 1) { sum += __shfl_xor(sum, o); sq += __shfl_xor(sq, o); }
    const float mean = sum * (1.f / CZ_);
    const float rstd = rsqrtf(sq * (1.f / CZ_) - mean * mean + 1e-5f);
    const int kb = s * 16;
    #pragma unroll
    for (int q = 0; q < 16; ++q)
      xln[r][kb + q] = (v[q] - mean) * rstd * gs[kb + q] + bs[kb + q];
  }
  __syncthreads();

  const int c = tid & (CZ_ - 1);
  const int h = tid >> 7;
  float accg[16], accp[16];
  #pragma unroll
  for (int q = 0; q < 16; ++q) { accg[q] = 0.f; accp[q] = 0.f; }
  #pragma unroll 2
  for (int k = 0; k < CZ_; k += 4) {
    const float wg0 = weg[(size_t)(k+0)*CZ_ + c], wg1 = weg[(size_t)(k+1)*CZ_ + c],
                wg2 = weg[(size_t)(k+2)*CZ_ + c], wg3 = weg[(size_t)(k+3)*CZ_ + c];
    const float wp0 = wep[(size_t)(k+0)*CZ_ + c], wp1 = wep[(size_t)(k+1)*CZ_ + c],
                wp2 = wep[(size_t)(k+2)*CZ_ + c], wp3 = wep[(size_t)(k+3)*CZ_ + c];
    #pragma unroll
    for (int rr = 0; rr < 16; ++rr) {
      const float4 xv = *(const float4*)&xln[h*16 + rr][k];
      accg[rr] = fmaf(xv.x, wg0, accg[rr]); accg[rr] = fmaf(xv.y, wg1, accg[rr]);
      accg[rr] = fmaf(xv.z, wg2, accg[rr]); accg[rr] = fmaf(xv.w, wg3, accg[rr]);
      accp[rr] = fmaf(xv.x, wp0, accp[rr]); accp[rr] = fmaf(xv.y, wp1, accp[rr]);
      accp[rr] = fmaf(xv.z, wp2, accp[rr]); accp[rr] = fmaf(xv.w, wp3, accp[rr]);
    }
  }
  const float bg = beg[c], bp = bep[c];
  #pragma unroll
  for (int rr = 0; rr < 16; ++rr) {
    const float gate = 1.f / (1.f + __expf(-(accg[rr] + bg)));
    edge2[(size_t)(row0 + h*16 + rr) * CZ_ + c] = gate * (accp[rr] + bp);
  }
}

// ------- K3: MFMA pair features, written in perm order (no atomics) -------
// Block: 256 thr (4 waves), 128 pair-slots. Wave w owns slots [32w,32w+32), M-tiles m=0,1.
// feat dword d of a slot packs bf16(ch=d) | bf16(ch=d+64)<<16.
__global__ __launch_bounds__(256, 2) void k_pairfeat(
    const int* __restrict__ perm, const int* __restrict__ ee,
    const int* __restrict__ sei, const int* __restrict__ dei,
    const unsigned short* __restrict__ nlb, const unsigned short* __restrict__ nrb,
    const float* __restrict__ trans, const unsigned short* __restrict__ frag,
    const float* __restrict__ bdg, const float* __restrict__ bdp,
    unsigned int* __restrict__ feat) {
  __shared__ unsigned short sfrag[40960];  // 64KB Bfrag + 16KB B2frag
  const int tid = threadIdx.x;

  #pragma unroll
  for (int i = 0; i < 20; ++i)
    ((float4*)sfrag)[i * 256 + tid] = ((const float4*)frag)[i * 256 + tid];

  const int lane = tid & 63;
  const int w = tid >> 6;
  const int g = lane >> 4;
  const int c15 = lane & 15;
  const int rowbase = blockIdx.x * 128 + w * 32;

  unsigned int nlu[2][8], nru[2][8];
  float dist[2];
  #pragma unroll
  for (int m = 0; m < 2; ++m) {
    const int slot = rowbase + m * 16 + c15;
    const int p = perm[slot];
    const int e0 = ee[p];
    const int e1 = ee[NP + p];
    const int n1 = sei[e1];
    const int n2 = dei[e0];
    const uint4 a = ((const uint4*)(nlb + (size_t)n1 * CG_))[0];
    const uint4 b = ((const uint4*)(nlb + (size_t)n1 * CG_))[1];
    nlu[m][0]=a.x; nlu[m][1]=a.y; nlu[m][2]=a.z; nlu[m][3]=a.w;
    nlu[m][4]=b.x; nlu[m][5]=b.y; nlu[m][6]=b.z; nlu[m][7]=b.w;
    const uint4 c = ((const uint4*)(nrb + (size_t)n2 * CG_))[0];
    const uint4 d = ((const uint4*)(nrb + (size_t)n2 * CG_))[1];
    nru[m][0]=c.x; nru[m][1]=c.y; nru[m][2]=c.z; nru[m][3]=c.w;
    nru[m][4]=d.x; nru[m][5]=d.y; nru[m][6]=d.z; nru[m][7]=d.w;
    const float dx = trans[n1*3+0] - trans[n2*3+0] + 1e-8f;
    const float dy = trans[n1*3+1] - trans[n2*3+1] + 1e-8f;
    const float dz = trans[n1*3+2] - trans[n2*3+2] + 1e-8f;
    dist[m] = sqrtf(fmaf(dx, dx, fmaf(dy, dy, dz * dz)));
  }
  __syncthreads();

  f32x4 acc[2][8], acc2[2][8];
  #pragma unroll
  for (int m = 0; m < 2; ++m)
    #pragma unroll
    for (int n = 0; n < 8; ++n) { acc[m][n] = (f32x4)0.f; acc2[m][n] = (f32x4)0.f; }

  const bool hiI = (lane & 32) != 0;   // selects i = 2ks+1
  const bool hiJ = (lane & 16) != 0;   // selects j-half 8..15

  // gate GEMM: K=256
  #pragma unroll
  for (int ks = 0; ks < 8; ++ks) {
    bf16x8 af[2];
    #pragma unroll
    for (int m = 0; m < 2; ++m) {
      const unsigned wv = nlu[m][ks];
      const float nli = __uint_as_float(hiI ? (wv & 0xFFFF0000u) : (wv << 16));
      #pragma unroll
      for (int ep = 0; ep < 4; ++ep) {
        const unsigned wr = hiJ ? nru[m][4 + ep] : nru[m][ep];
        const float j0 = __uint_as_float(wr << 16);
        const float j1 = __uint_as_float(wr & 0xFFFF0000u);
        af[m][2*ep]   = (short)f2bf(nli * j0);
        af[m][2*ep+1] = (short)f2bf(nli * j1);
      }
    }
    #pragma unroll
    for (int n = 0; n < 8; ++n) {
      const bf16x8 bf = *(const bf16x8*)(sfrag + ((size_t)((n * 8 + ks) * 64 + lane)) * 8);
      acc[0][n] = __builtin_amdgcn_mfma_f32_16x16x32_bf16(af[0], bf, acc[0][n], 0, 0, 0);
      acc[1][n] = __builtin_amdgcn_mfma_f32_16x16x32_bf16(af[1], bf, acc[1][n], 0, 0, 0);
    }
  }

  // RBF GEMM: K=64
  const float MU_STEP = 20.f / 63.f;
  const float INV_SIG = 64.f / 20.f;
  #pragma unroll
  for (int ks2 = 0; ks2 < 2; ++ks2) {
    bf16x8 a2[2];
    const int k2b = ks2 * 32 + g * 8;
    #pragma unroll
    for (int m = 0; m < 2; ++m) {
      #pragma unroll
      for (int e = 0; e < 8; ++e) {
        const float mu = (float)(k2b + e) * MU_STEP;
        const float u = (dist[m] - mu) * INV_SIG;
        a2[m][e] = (short)f2bf(__expf(-u * u));
      }
    }
    #pragma unroll
    for (int n = 0; n < 8; ++n) {
      const bf16x8 b2 = *(const bf16x8*)(sfrag + 32768 + ((size_t)((n * 2 + ks2) * 64 + lane)) * 8);
      acc2[0][n] = __builtin_amdgcn_mfma_f32_16x16x32_bf16(a2[0], b2, acc2[0][n], 0, 0, 0);
      acc2[1][n] = __builtin_amdgcn_mfma_f32_16x16x32_bf16(a2[1], b2, acc2[1][n], 0, 0, 0);
    }
  }

  float bdgv[8], bdpv[8];
  #pragma unroll
  for (int n = 0; n < 8; ++n) { bdgv[n] = bdg[n*16 + c15]; bdpv[n] = bdp[n*16 + c15]; }

  #pragma unroll
  for (int m = 0; m < 2; ++m) {
    #pragma unroll
    for (int n = 0; n < 4; ++n) {
      #pragma unroll
      for (int r = 0; r < 4; ++r) {
        const float glo = __builtin_amdgcn_rcpf(1.f + __expf(-(acc[m][n][r] + bdgv[n])));
        const float ghi = __builtin_amdgcn_rcpf(1.f + __expf(-(acc[m][n+4][r] + bdgv[n+4])));
        const float lo = glo * (acc2[m][n][r] + bdpv[n]);
        const float hi = ghi * (acc2[m][n+4][r] + bdpv[n+4]);
        const unsigned u = (unsigned)f2bf(lo) | ((unsigned)f2bf(hi) << 16);
        const int row = rowbase + m * 16 + g * 4 + r;
        feat[(size_t)row * 64 + n * 16 + c15] = u;
      }
    }
  }
}

// ------- K_segsum: per-edge sorted gather-sum, multiply edge2 in place -------
__global__ __launch_bounds__(64) void k_segsum(
    const int* __restrict__ start, const int* __restrict__ perm,
    const unsigned int* __restrict__ feat, float* __restrict__ e2) {
  __shared__ int lst[512];
  const int e = blockIdx.x;
  const int t = threadIdx.x;
  const int s0 = start[e], s1 = start[e + 1];
  const int deg = s1 - s0;
  float slo = 0.f, shi = 0.f;
  if (deg <= 512) {
    for (int i = t; i < deg; i += 64) lst[i] = (perm[s0 + i] << 9) | i;
    __syncthreads();
    if (t == 0) {
      for (int a = 1; a < deg; ++a) {
        const int v = lst[a];
        int b = a - 1;
        while (b >= 0 && lst[b] > v) { lst[b + 1] = lst[b]; --b; }
        lst[b + 1] = v;
      }
    }
    __syncthreads();
    for (int j = 0; j < deg; ++j) {
      const int slot = s0 + (lst[j] & 511);
      const unsigned u = feat[(size_t)slot * 64 + t];
      slo += __uint_as_float(u << 16);
      shi += __uint_as_float(u & 0xFFFF0000u);
    }
  } else {  // unreachable for this input scale; correctness fallback
    for (int j = 0; j < deg; ++j) {
      const unsigned u = feat[(size_t)(s0 + j) * 64 + t];
      slo += __uint_as_float(u << 16);
      shi += __uint_as_float(u & 0xFFFF0000u);
    }
  }
  const float p0 = e2[(size_t)e * CZ_ + t];
  const float p1 = e2[(size_t)e * CZ_ + 64 + t];
  e2[(size_t)e * CZ_ + t] = slo * p0;
  e2[(size_t)e * CZ_ + 64 + t] = shi * p1;
}

// ------- K4: out = (LN(prod)@w_lo+b_lo) * sigmoid(LN(dst)@w_og+b_og) -------
__global__ __launch_bounds__(256) void k_final(
    const float* __restrict__ prod, const float* __restrict__ def,
    const float* __restrict__ go, const float* __restrict__ bo,
    const float* __restrict__ gd, const float* __restrict__ bd,
    const float* __restrict__ wlo, const float* __restrict__ blo,
    const float* __restrict__ wog, const float* __restrict__ bog,
    float* __restrict__ out) {
  __shared__ float x1[32][132];
  __shared__ float x2[32][132];
  const int tid = threadIdx.x;
  const int row0 = blockIdx.x * 32;
  {
    const int r = tid >> 3, s = tid & 7;
    const int kb = s * 16;
    float v[16];
    {
      const float* __restrict__ ap = prod + (size_t)(row0 + r) * CZ_ + kb;
      #pragma unroll
      for (int q = 0; q < 4; ++q) {
        const float4 a4 = *(const float4*)(ap + 4*q);
        v[4*q+0]=a4.x; v[4*q+1]=a4.y; v[4*q+2]=a4.z; v[4*q+3]=a4.w;
      }
      float sum = 0.f, sq = 0.f;
      #pragma unroll
      for (int q = 0; q < 16; ++q) { sum += v[q]; sq = fmaf(v[q], v[q], sq); }
      #pragma unroll
      for (int o = 1; o < 8; o <<= 1) { sum += __shfl_xor(sum, o); sq += __shfl_xor(sq, o); }
      const float mean = sum * (1.f / CZ_);
      const float rstd = rsqrtf(sq * (1.f / CZ_) - mean * mean + 1e-5f);
      #pragma unroll
      for (int q = 0; q < 16; ++q)
        x1[r][kb+q] = (v[q] - mean) * rstd * go[kb+q] + bo[kb+q];
    }
    {
      const float* __restrict__ dp = def + (size_t)(row0 + r) * CZ_ + kb;
      #pragma unroll
      for (int q = 0; q < 4; ++q) {
        const float4 a4 = *(const float4*)(dp + 4*q);
        v[4*q+0]=a4.x; v[4*q+1]=a4.y; v[4*q+2]=a4.z; v[4*q+3]=a4.w;
      }
      float sum = 0.f, sq = 0.f;
      #pragma unroll
      for (int q = 0; q < 16; ++q) { sum += v[q]; sq = fmaf(v[q], v[q], sq); }
      #pragma unroll
      for (int o = 1; o < 8; o <<= 1) { sum += __shfl_xor(sum, o); sq += __shfl_xor(sq, o); }
      const float mean = sum * (1.f / CZ_);
      const float rstd = rsqrtf(sq * (1.f / CZ_) - mean * mean + 1e-5f);
      #pragma unroll
      for (int q = 0; q < 16; ++q)
        x2[r][kb+q] = (v[q] - mean) * rstd * gd[kb+q] + bd[kb+q];
    }
  }
  __syncthreads();

  const int c = tid & (CZ_ - 1);
  const int h = tid >> 7;
  float accy[16], accg[16];
  #pragma unroll
  for (int q = 0; q < 16; ++q) { accy[q] = 0.f; accg[q] = 0.f; }
  #pragma unroll 2
  for (int k = 0; k < CZ_; k += 4) {
    const float wl0 = wlo[(size_t)(k+0)*CZ_ + c], wl1 = wlo[(size_t)(k+1)*CZ_ + c],
                wl2 = wlo[(size_t)(k+2)*CZ_ + c], wl3 = wlo[(size_t)(k+3)*CZ_ + c];
    const float wo0 = wog[(size_t)(k+0)*CZ_ + c], wo1 = wog[(size_t)(k+1)*CZ_ + c],
                wo2 = wog[(size_t)(k+2)*CZ_ + c], wo3 = wog[(size_t)(k+3)*CZ_ + c];
    #pragma unroll
    for (int rr = 0; rr < 16; ++rr) {
      const float4 xv1 = *(const float4*)&x1[h*16 + rr][k];
      const float4 xv2 = *(const float4*)&x2[h*16 + rr][k];
      accy[rr] = fmaf(xv1.x, wl0, accy[rr]); accy[rr] = fmaf(xv1.y, wl1, accy[rr]);
      accy[rr] = fmaf(xv1.z, wl2, accy[rr]); accy[rr] = fmaf(xv1.w, wl3, accy[rr]);
      accg[rr] = fmaf(xv2.x, wo0, accg[rr]); accg[rr] = fmaf(xv2.y, wo1, accg[rr]);
      accg[rr] = fmaf(xv2.z, wo2, accg[rr]); accg[rr] = fmaf(xv2.w, wo3, accg[rr]);
    }
  }
  const float bl = blo[c], bgv = bog[c];
  #pragma unroll
  for (int rr = 0; rr < 16; ++rr) {
    const float y = accy[rr] + bl;
    const float gsig = 1.f / (1.f + __expf(-(accg[rr] + bgv)));
    out[(size_t)(row0 + h*16 + rr) * CZ_ + c] = y * gsig;
  }
}

extern "C" void kernel_launch(void* const* d_in, const int* in_sizes, int n_in,
                              void* d_out, int out_size, void* d_ws, size_t ws_size,
                              hipStream_t stream) {
  const float* nf     = (const float*)d_in[0];
  const float* trans  = (const float*)d_in[1];
  const float* dst_ef = (const float*)d_in[2];
  const int*   dst_ei = (const int*)d_in[3];
  const float* src_ef = (const float*)d_in[4];
  const int*   src_ei = (const int*)d_in[5];
  const int*   ee     = (const int*)d_in[6];
  const float* w_nl  = (const float*)d_in[7];  const float* b_nl  = (const float*)d_in[8];
  const float* w_nr  = (const float*)d_in[9];  const float* b_nr  = (const float*)d_in[10];
  const float* g_dst = (const float*)d_in[11]; const float* bt_dst= (const float*)d_in[12];
  const float* g_src = (const float*)d_in[13]; const float* bt_src= (const float*)d_in[14];
  const float* w_ep  = (const float*)d_in[15]; const float* b_ep  = (const float*)d_in[16];
  const float* w_eg  = (const float*)d_in[17]; const float* b_eg  = (const float*)d_in[18];
  const float* w_dg  = (const float*)d_in[19]; const float* b_dg  = (const float*)d_in[20];
  const float* w_dp  = (const float*)d_in[21]; const float* b_dp  = (const float*)d_in[22];
  const float* g_out = (const float*)d_in[23]; const float* bt_out= (const float*)d_in[24];
  const float* w_lo  = (const float*)d_in[25]; const float* b_lo  = (const float*)d_in[26];
  const float* w_og  = (const float*)d_in[27]; const float* b_og  = (const float*)d_in[28];

  char* ws = (char*)d_ws;
  size_t off = 0;
  unsigned int* feat = (unsigned int*)(ws + off); off += (size_t)NP * 64 * 4;          // 67.1MB
  float*        e2   = (float*)(ws + off);        off += (size_t)NE * CZ_ * 4;          // 16.8MB
  unsigned short* nlb = (unsigned short*)(ws + off); off += (size_t)NN * CG_ * 2;
  unsigned short* nrb = (unsigned short*)(ws + off); off += (size_t)NN * CG_ * 2;
  unsigned short* frag = (unsigned short*)(ws + off); off += 81920;                     // 80KB
  int* hist  = (int*)(ws + off); off += 32768 * 4;
  int* start = (int*)(ws + off); off += 32772 * 4;
  int* cnt2  = (int*)(ws + off); off += 32768 * 4;
  int* perm  = (int*)(ws + off); off += (size_t)NP * 4;

  // zero hist..cnt2 span (start overwritten by k_scan)
  hipMemsetAsync(hist, 0, (char*)perm - (char*)hist, stream);

  k_nodeproj<<<NN, 64, 0, stream>>>(nf, w_nl, b_nl, w_nr, b_nr, nlb, nrb);
  k_prepB<<<160, 256, 0, stream>>>(w_dg, w_dp, frag);
  k_hist<<<NP / 256, 256, 0, stream>>>(ee, hist);
  k_scan<<<1, 1024, 0, stream>>>(hist, start);
  k_scatter<<<NP / 256, 256, 0, stream>>>(ee, start, cnt2, perm);
  k_edge2<<<NE / 32, 256, 0, stream>>>(src_ef, g_src, bt_src, w_eg, b_eg, w_ep, b_ep, e2);
  k_pairfeat<<<NP / 128, 256, 0, stream>>>(perm, ee, src_ei, dst_ei, nlb, nrb, trans,
                                           frag, b_dg, b_dp, feat);
  k_segsum<<<NE, 64, 0, stream>>>(start, perm, feat, e2);
  k_final<<<NE / 32, 256, 0, stream>>>(e2, dst_ef, g_out, bt_out, g_dst, bt_dst,
                                       w_lo, b_lo, w_og, b_og, (float*)d_out);
}